// Round 5
// baseline (209.073 us; speedup 1.0000x reference)
//
#include <hip/hip_runtime.h>
#include <math.h>

#define NGRID 9801
#define NB 11            // blocks per dim (both scales)
#define NBLK (NB*NB)     // 121
#define BATCH 16
#define NFEAT 36

// ---------------- tables ----------------
__global__ void init_tables(float* __restrict__ rgam, float* __restrict__ convt,
                            float* __restrict__ meanf, float* __restrict__ w1d) {
    int i = blockIdx.x * blockDim.x + threadIdx.x;
    if (i < NGRID) {
        double a = (double)(float)(0.2 + 0.001 * (double)i);  // match float32 grid
        double g1 = lgamma(1.0 / a);
        double g2 = lgamma(2.0 / a);
        double g3 = lgamma(3.0 / a);
        rgam[i]  = (float)exp(2.0 * g2 - g1 - g3);
        convt[i] = (float)sqrt(exp(g1 - g3));
        meanf[i] = (float)exp(g2 - g1);
    }
    if (i == 0) {
        double g[7], s = 0.0;
        for (int k = 0; k < 7; ++k) { double d = (double)(k - 3); g[k] = exp(-d * d * 18.0 / 49.0); s += g[k]; }
        for (int k = 0; k < 7; ++k) w1d[k] = (float)(g[k] / s);
    }
}

__device__ __forceinline__ float bperm(int addr, float v) {
    return __int_as_float(__builtin_amdgcn_ds_bpermute(addr, __float_as_int(v)));
}

// ---------------- fully fused MSCN + in-register per-block stats ----------------
// One WG per (NIQE block, batch). 4 waves:
//   K=96: 2 slabs(48 cols) x 2 strips(48 rows); K=48: 1 slab x 4 strips(12 rows).
// Sliding-window separable 7x7 conv; norm kept in registers only. The 25 AGGD
// sums (5 signals x {cl,cr,sl2,sr2,sab}) accumulate during the walk. Block-
// circular wrap terms crossing wave boundaries contribute 0 in the walk
// (zeroed operands) and are patched from small LDS seam buffers afterwards.
template <int K, bool WDS>
__global__ __launch_bounds__(256) void fused_mscn_stats(
        const float* __restrict__ img, float* __restrict__ dsout,
        const float* __restrict__ w1d, float* __restrict__ stats) {
    constexpr int NSLAB = K / 48;
    constexpr int NSTRIP = 4 / NSLAB;
    constexpr int SROWS = K / NSTRIP;
    constexpr int W = K * NB;
    constexpr int H = W;

    __shared__ float lastrow[NSTRIP][K];            // each strip's last norm row
    __shared__ float edgeL[NSTRIP][NSLAB][SROWS];   // per-row slab-edge norm (K=96)
    __shared__ float edgeR[NSTRIP][NSLAB][SROWS];
    __shared__ float red[4][25];

    const int tid = threadIdx.x;
    const int lane = tid & 63;
    const int wv = tid >> 6;
    const int slab = wv % NSLAB;
    const int strip = wv / NSLAB;
    const int bIdx = blockIdx.x;
    const int b = blockIdx.y;
    const int bh = bIdx / NB, bw = bIdx % NB;
    const int x0 = bw * K + slab * 48;
    const int gx = x0 - 3 + lane;
    const int gxc = min(max(gx, 0), W - 1);
    const int r0 = bh * K + strip * SROWS;
    const int basem3 = (lane - 3) << 2;
    const bool act = (lane >= 3) && (lane <= 50);
    // circular-in-block shift addresses for the product terms
    int am1, ap1;
    if constexpr (NSLAB == 1) {
        am1 = ((lane == 3) ? 50 : (lane - 1)) << 2;
        ap1 = ((lane == 50) ? 3 : (lane + 1)) << 2;
    } else {
        am1 = ((lane - 1) & 63) << 2;   // lane3 reads zeroed lane2 -> fixup later
        ap1 = ((lane + 1) & 63) << 2;   // lane50 reads zeroed lane51 -> fixup later
    }

    const float* im = img + (size_t)b * H * W + gxc;
    const float w0=w1d[0], w1=w1d[1], w2=w1d[2], w3=w1d[3], w4=w1d[4], w5=w1d[5], w6=w1d[6];

    auto ld = [&](int r) -> float {
        int rc = min(max(r, 0), H - 1);
        return im[(size_t)rc * W];
    };
    auto hconv = [&](float v, float& omu, float& om2) {
        float a0 = bperm(basem3,      v);
        float a1 = bperm(basem3 + 4,  v);
        float a2 = bperm(basem3 + 8,  v);
        float a4 = bperm(basem3 + 16, v);
        float a5 = bperm(basem3 + 20, v);
        float a6 = bperm(basem3 + 24, v);
        omu = ((w0*a0 + w1*a1) + (w2*a2 + w3*v)) + ((w4*a4 + w5*a5) + w6*a6);
        om2 = ((w0*a0*a0 + w1*a1*a1) + (w2*a2*a2 + w3*v*v)) + ((w4*a4*a4 + w5*a5*a5) + w6*a6*a6);
    };

    float acc[5][5];
    #pragma unroll
    for (int s = 0; s < 5; ++s)
        #pragma unroll
        for (int q = 0; q < 5; ++q) acc[s][q] = 0.f;

    auto upd = [&](int s, float v) {
        float vn = fminf(v, 0.f);
        float vp = fmaxf(v, 0.f);
        acc[s][2] = fmaf(vn, vn, acc[s][2]);   // sl2
        acc[s][3] = fmaf(vp, vp, acc[s][3]);   // sr2
        acc[s][4] += vp - vn;                  // sum |v|
        acc[s][0] += (v < 0.f) ? 1.f : 0.f;    // cl
        acc[s][1] += (v > 0.f) ? 1.f : 0.f;    // cr
    };

    float m0,m1,mm2,m3,m4,m5,m6, q0,q1,q2,q3,q4,q5,q6;
    float rA, rB, rC, dsSave = 0.f;
    float vN = ld(r0 - 3);
    { float v = vN; vN = ld(r0 - 2); hconv(v, m0,  q0); }
    { float v = vN; vN = ld(r0 - 1); hconv(v, m1,  q1); }
    { float v = vN; vN = ld(r0 + 0); hconv(v, mm2, q2); }
    { float v = vN; vN = ld(r0 + 1); hconv(v, m3,  q3); rA = v; }
    { float v = vN; vN = ld(r0 + 2); hconv(v, m4,  q4); rB = v; }
    { float v = vN; vN = ld(r0 + 3); hconv(v, m5,  q5); rC = v; }

    const bool dsw = WDS && (lane & 1) && (lane >= 3) && (lane <= 49);
    float prev = 0.f, firstN = 0.f;

    #pragma unroll 6
    for (int yy = 0; yy < SROWS; ++yy) {
        const int y = r0 + yy;
        float v = vN; vN = ld(y + 4);
        hconv(v, m6, q6);
        float rD = v;
        float mu = ((w0*m0 + w1*m1) + (w2*mm2 + w3*m3)) + ((w4*m4 + w5*m5) + w6*m6);
        float s2 = ((w0*q0 + w1*q1) + (w2*q2 + w3*q3)) + ((w4*q4 + w5*q5) + w6*q6);
        float sig = __builtin_amdgcn_sqrtf(fabsf(s2 - mu * mu));
        float nrm = (rA - mu) * __builtin_amdgcn_rcpf(sig + 1.0f);
        float cur = act ? nrm : 0.f;

        float curL = bperm(am1, cur);
        float prvL = bperm(am1, prev);
        float prvR = bperm(ap1, prev);
        upd(0, cur);
        upd(1, cur * curL);
        upd(2, cur * prev);
        upd(3, cur * prvL);
        upd(4, cur * prvR);

        if (yy == 0) firstN = cur;
        if constexpr (NSLAB == 2) {
            if (lane == 3)  edgeL[strip][slab][yy] = cur;
            if (lane == 50) edgeR[strip][slab][yy] = cur;
        }
        if (yy == SROWS - 1 && act) lastrow[strip][slab * 48 + lane - 3] = cur;

        if constexpr (WDS) {
            float hs = rA + __shfl_down(rA, 1);
            if ((y & 1) == 0) dsSave = hs;
            else if (dsw)
                dsout[((size_t)b * (H / 2) + (y >> 1)) * (W / 2) + (gx >> 1)] = 0.25f * (dsSave + hs);
        }

        prev = cur;
        m0=m1; m1=mm2; mm2=m3; m3=m4; m4=m5; m5=m6;
        q0=q1; q1=q2; q2=q3; q3=q4; q4=q5; q5=q6;
        rA=rB; rB=rC; rC=rD;
    }
    __syncthreads();

    // ---- row-seam fixup: products of row r0 with block-circular previous row ----
    {
        const int ps = (strip + NSTRIP - 1) % NSTRIP;
        int j  = slab * 48 + (lane - 3);
        int js = act ? j : 0;
        int jm1 = (js + K - 1) % K;
        int jp1 = (js + 1) % K;
        float pv  = act ? lastrow[ps][js]  : 0.f;
        float pvL = act ? lastrow[ps][jm1] : 0.f;
        float pvR = act ? lastrow[ps][jp1] : 0.f;
        upd(2, firstN * pv);
        upd(3, firstN * pvL);
        upd(4, firstN * pvR);
    }

    // ---- column-seam fixup (K=96 only): slab-edge wrap products ----
    if constexpr (NSLAB == 2) {
        if (lane < SROWS) {
            int r = lane;
            if (slab == 0) {
                float c0  = edgeL[strip][0][r];   // n[r][0]
                float e95 = edgeR[strip][1][r];   // n[r][95]
                upd(1, c0 * e95);
                if (r > 0) {
                    upd(3, c0 * edgeR[strip][1][r - 1]);
                    upd(4, edgeR[strip][0][r] * edgeL[strip][1][r - 1]);  // col47 * n[r-1][48]
                }
            } else {
                float c48 = edgeL[strip][1][r];   // n[r][48]
                float e47 = edgeR[strip][0][r];   // n[r][47]
                upd(1, c48 * e47);
                if (r > 0) {
                    upd(3, c48 * edgeR[strip][0][r - 1]);
                    upd(4, edgeR[strip][1][r] * edgeL[strip][0][r - 1]); // col95 * n[r-1][0]
                }
            }
        }
    }

    // ---- reduce 25 sums ----
    #pragma unroll
    for (int off = 32; off >= 1; off >>= 1)
        #pragma unroll
        for (int s = 0; s < 5; ++s)
            #pragma unroll
            for (int q = 0; q < 5; ++q)
                acc[s][q] += __shfl_down(acc[s][q], off);

    if (lane == 0) {
        #pragma unroll
        for (int s = 0; s < 5; ++s)
            #pragma unroll
            for (int q = 0; q < 5; ++q) red[wv][s * 5 + q] = acc[s][q];
    }
    __syncthreads();
    if (tid < 25) {
        stats[((size_t)b * NBLK + bIdx) * 25 + tid] =
            red[0][tid] + red[1][tid] + red[2][tid] + red[3][tid];
    }
}

// ---------------- AGGD closed-form + binary-search argmin ----------------
__global__ __launch_bounds__(256) void aggd_kernel(
        const float* __restrict__ stats1, const float* __restrict__ stats2,
        const float* __restrict__ rgam, const float* __restrict__ convt,
        const float* __restrict__ meanf, float* __restrict__ feats) {
    __shared__ float rg[NGRID];
    for (int i = threadIdx.x; i < NGRID; i += 256) rg[i] = rgam[i];
    __syncthreads();

    int gid = blockIdx.x * 256 + threadIdx.x;
    if (gid >= 2 * BATCH * NBLK * 5) return;
    int s = gid % 5; int t = gid / 5;
    int blk = t % NBLK; t /= NBLK;
    int b = t % BATCH; int scale = t / BATCH;

    const float* st = (scale ? stats2 : stats1) + ((size_t)b * NBLK + blk) * 25 + s * 5;
    float cl = st[0], cr = st[1], sl2 = st[2], sr2 = st[3], sab = st[4];
    float n = scale ? (48.f * 48.f) : (96.f * 96.f);

    float lstd = sqrtf(sl2 / (cl + 1e-8f));
    float rstd = sqrtf(sr2 / (cr + 1e-8f));
    float gh = lstd / rstd;
    float mab = sab / n;
    float msq = (sl2 + sr2) / n;
    float rhat = mab * mab / msq;
    float g2 = gh * gh;
    float x = rhat * (gh * g2 + 1.f) * (gh + 1.f) / ((g2 + 1.f) * (g2 + 1.f));

    // lower_bound: first index with rg[i] >= x  (rg monotone increasing)
    int lo = 0, hi = NGRID;
    while (lo < hi) {
        int mid = (lo + hi) >> 1;
        if (rg[mid] < x) lo = mid + 1; else hi = mid;
    }
    int gi;
    if (lo <= 0) gi = 0;
    else if (lo >= NGRID) gi = NGRID - 1;
    else {
        float dlo = x - rg[lo - 1];   // > 0
        float dhi = rg[lo] - x;       // >= 0
        gi = (dlo <= dhi) ? lo - 1 : lo;   // tie -> lower index (first-min)
    }

    float alpha = (float)(0.2 + 0.001 * (double)gi);
    float cv = convt[gi];
    float lb = lstd * cv, rb = rstd * cv;
    float* fo = feats + ((size_t)b * NBLK + blk) * NFEAT + (scale ? 18 : 0);
    if (s == 0) {
        fo[0] = alpha;
        fo[1] = 0.5f * (lb + rb);
    } else {
        int o = 2 + (s - 1) * 4;
        fo[o]     = alpha;
        fo[o + 1] = (rb - lb) * meanf[gi];
        fo[o + 2] = lb;
        fo[o + 3] = rb;
    }
}

// ---------------- per-batch covariance + solve + score ----------------
// cov = (cov_pris + cov_dist)/2 is SPD (lambda_min >= 0.25) -> no pivoting.
__global__ __launch_bounds__(256) void score_kernel(
        const float* __restrict__ feats, const float* __restrict__ mu_pris,
        const float* __restrict__ cov_pris, float* __restrict__ out) {
    __shared__ float F[NBLK][NFEAT];
    __shared__ double mu[NFEAT];
    __shared__ double A[NFEAT][NFEAT + 1];
    __shared__ double dff[NFEAT];
    __shared__ double fac[NFEAT];
    __shared__ double xs[NFEAT];
    int b = blockIdx.x, tid = threadIdx.x;
    const float* fp = feats + (size_t)b * NBLK * NFEAT;
    for (int i = tid; i < NBLK * NFEAT; i += 256) F[i / NFEAT][i % NFEAT] = fp[i];
    __syncthreads();
    if (tid < NFEAT) {
        double s = 0.0;
        for (int n = 0; n < NBLK; ++n) s += (double)F[n][tid];
        mu[tid] = s / (double)NBLK;
        dff[tid] = (double)mu_pris[tid] - mu[tid];
    }
    __syncthreads();
    for (int e = tid; e < NFEAT * NFEAT; e += 256) {
        int f = e / NFEAT, g = e % NFEAT;
        double mf = mu[f], mg = mu[g];
        double s = 0.0;
        for (int n = 0; n < NBLK; ++n) s += ((double)F[n][f] - mf) * ((double)F[n][g] - mg);
        A[f][g] = (s / (double)(NBLK - 1) + (double)cov_pris[f * NFEAT + g]) * 0.5;
    }
    if (tid < NFEAT) A[tid][NFEAT] = dff[tid];
    __syncthreads();
    // forward elimination, parallel rows (no pivot search)
    for (int k = 0; k < NFEAT - 1; ++k) {
        if (tid > k && tid < NFEAT) fac[tid] = A[tid][k] / A[k][k];
        __syncthreads();
        for (int e = tid; e < NFEAT * (NFEAT + 1); e += 256) {
            int r = e / (NFEAT + 1), c = e % (NFEAT + 1);
            if (r > k && c > k) A[r][c] -= fac[r] * A[k][c];
        }
        __syncthreads();
    }
    // back substitution, parallel column updates
    for (int i = NFEAT - 1; i >= 0; --i) {
        if (tid == i) xs[i] = A[i][NFEAT] / A[i][i];
        __syncthreads();
        if (tid < i) A[tid][NFEAT] -= A[tid][i] * xs[i];
        __syncthreads();
    }
    if (tid == 0) {
        double quad = 0.0;
        for (int i = 0; i < NFEAT; ++i) quad += dff[i] * xs[i];
        out[b] = (float)sqrt(fmax(quad, 0.0));
    }
}

// ---------------- launch ----------------
extern "C" void kernel_launch(void* const* d_in, const int* in_sizes, int n_in,
                              void* d_out, int out_size, void* d_ws, size_t ws_size,
                              hipStream_t stream) {
    const float* img      = (const float*)d_in[0];
    const float* mu_pris  = (const float*)d_in[1];
    const float* cov_pris = (const float*)d_in[2];
    float* out = (float*)d_out;
    float* ws = (float*)d_ws;

    float* rgam  = ws;                 // 9801 (pad to 9856)
    float* convt = rgam + 9856;
    float* meanf = convt + 9856;
    float* w1d   = meanf + 9856;       // 8
    float* stats1 = w1d + 8;                           // 16*121*25
    float* stats2 = stats1 + BATCH * NBLK * 25;
    float* feats  = stats2 + BATCH * NBLK * 25;        // 16*121*36
    float* dsimg  = feats + BATCH * NBLK * NFEAT;      // 16*528*528

    init_tables<<<(NGRID + 255) / 256, 256, 0, stream>>>(rgam, convt, meanf, w1d);

    fused_mscn_stats<96, true><<<dim3(NBLK, BATCH), 256, 0, stream>>>(
        img, dsimg, w1d, stats1);
    fused_mscn_stats<48, false><<<dim3(NBLK, BATCH), 256, 0, stream>>>(
        dsimg, nullptr, w1d, stats2);

    aggd_kernel<<<(2 * BATCH * NBLK * 5 + 255) / 256, 256, 0, stream>>>(
        stats1, stats2, rgam, convt, meanf, feats);

    score_kernel<<<BATCH, 256, 0, stream>>>(feats, mu_pris, cov_pris, out);
}

// Round 6
// 178.054 us; speedup vs baseline: 1.1742x; 1.1742x over previous
//
#include <hip/hip_runtime.h>
#include <math.h>

#define NGRID 9801
#define NB 11            // blocks per dim (both scales)
#define NBLK (NB*NB)     // 121
#define BATCH 16
#define NFEAT 36

// ---------------- tables ----------------
__global__ void init_tables(float* __restrict__ rgam, float* __restrict__ convt,
                            float* __restrict__ meanf, float* __restrict__ w1d) {
    int i = blockIdx.x * blockDim.x + threadIdx.x;
    if (i < NGRID) {
        double a = (double)(float)(0.2 + 0.001 * (double)i);  // match float32 grid
        double g1 = lgamma(1.0 / a);
        double g2 = lgamma(2.0 / a);
        double g3 = lgamma(3.0 / a);
        rgam[i]  = (float)exp(2.0 * g2 - g1 - g3);
        convt[i] = (float)sqrt(exp(g1 - g3));
        meanf[i] = (float)exp(g2 - g1);
    }
    if (i == 0) {
        double g[7], s = 0.0;
        for (int k = 0; k < 7; ++k) { double d = (double)(k - 3); g[k] = exp(-d * d * 18.0 / 49.0); s += g[k]; }
        for (int k = 0; k < 7; ++k) w1d[k] = (float)(g[k] / s);
    }
}

__device__ __forceinline__ float bperm(int addr, float v) {
    return __int_as_float(__builtin_amdgcn_ds_bpermute(addr, __float_as_int(v)));
}

// ---------------- fused MSCN + in-register per-block stats (software-pipelined) ----
// One WG per (NIQE block, batch). 4 waves:
//   K=96: 2 slabs(48 cols) x 2 strips(48 rows); K=48: 1 slab x 4 strips(12 rows).
// Pipeline invariant: no ds_bpermute result is consumed in the iteration that
// issues it. Stats for row y-1 run (pure VALU) at the top of iteration y.
// Counts cl/cr accumulate on the scalar unit via ballot+popcount.
// Stats layout per (batch,block), 25 floats: [s*3 +{sr2,ssq,sab}] s=0..4, then
// [15 + s*2 + {cl,cr}].
template <int K, bool WDS>
__global__ __launch_bounds__(256) void fused_mscn_stats(
        const float* __restrict__ img, float* __restrict__ dsout,
        const float* __restrict__ w1d, float* __restrict__ stats) {
    constexpr int NSLAB = K / 48;
    constexpr int NSTRIP = 4 / NSLAB;
    constexpr int SROWS = K / NSTRIP;
    constexpr int W = K * NB;
    constexpr int H = W;

    __shared__ float lastrow[NSTRIP][K];            // each strip's last norm row
    __shared__ float edgeL[NSTRIP][NSLAB][SROWS];   // per-row slab-edge norm (K=96)
    __shared__ float edgeR[NSTRIP][NSLAB][SROWS];
    __shared__ float redf[4][15];
    __shared__ float redc[4][10];

    const int tid = threadIdx.x;
    const int lane = tid & 63;
    const int wv = tid >> 6;
    const int slab = wv % NSLAB;
    const int strip = wv / NSLAB;
    const int bIdx = blockIdx.x;
    const int b = blockIdx.y;
    const int bh = bIdx / NB, bw = bIdx % NB;
    const int x0 = bw * K + slab * 48;
    const int gx = x0 - 3 + lane;
    const int gxc = min(max(gx, 0), W - 1);
    const int r0 = bh * K + strip * SROWS;
    const int basem3 = (lane - 3) << 2;
    const bool act = (lane >= 3) && (lane <= 50);
    int am1, ap1;
    if constexpr (NSLAB == 1) {
        am1 = ((lane == 3) ? 50 : (lane - 1)) << 2;
        ap1 = ((lane == 50) ? 3 : (lane + 1)) << 2;
    } else {
        am1 = ((lane - 1) & 63) << 2;   // lane3 reads zeroed lane2 -> fixup later
        ap1 = ((lane + 1) & 63) << 2;   // lane50 reads zeroed lane51 -> fixup later
    }

    const float* im = img + (size_t)b * H * W + gxc;
    const float w0=w1d[0], w1=w1d[1], w2=w1d[2], w3=w1d[3], w4=w1d[4], w5=w1d[5], w6=w1d[6];

    auto ld = [&](int r) -> float {
        int rc = min(max(r, 0), H - 1);
        return im[(size_t)rc * W];
    };

    // pending horizontal-conv inputs (bperms of raw row, issued one iter early)
    float pa0, pa1, pa2, pa4, pa5, pa6, vHp;
    auto issue_raw = [&](float v) {
        pa0 = bperm(basem3,      v);
        pa1 = bperm(basem3 + 4,  v);
        pa2 = bperm(basem3 + 8,  v);
        pa4 = bperm(basem3 + 16, v);
        pa5 = bperm(basem3 + 20, v);
        pa6 = bperm(basem3 + 24, v);
        vHp = v;
    };
    auto combine_raw = [&](float& om, float& oq) {
        om = ((w0*pa0 + w1*pa1) + (w2*pa2 + w3*vHp)) + ((w4*pa4 + w5*pa5) + w6*pa6);
        oq = ((w0*pa0*pa0 + w1*pa1*pa1) + (w2*pa2*pa2 + w3*vHp*vHp))
           + ((w4*pa4*pa4 + w5*pa5*pa5) + w6*pa6*pa6);
    };

    float acc[5][3];
    #pragma unroll
    for (int s = 0; s < 5; ++s) { acc[s][0] = acc[s][1] = acc[s][2] = 0.f; }
    int cl[5] = {0,0,0,0,0}, cr[5] = {0,0,0,0,0};

    auto upd = [&](int s, float v) {
        float vp = fmaxf(v, 0.f);
        acc[s][0] = fmaf(vp, vp, acc[s][0]);   // sr2
        acc[s][1] = fmaf(v, v, acc[s][1]);     // ssq (sl2 = ssq - sr2 later)
        acc[s][2] += fabsf(v);                 // sum |v|
        cl[s] += __popcll(__ballot(v < 0.f));  // scalar-unit counts
        cr[s] += __popcll(__ballot(v > 0.f));
    };

    // prologue: fill 7-row hconv ring (rows r0-3 .. r0+3) + pend row r0+4
    float mr0,mr1,mr2,mr3,mr4,mr5,mr6, qr0,qr1,qr2,qr3,qr4,qr5,qr6;
    float rA, rB, rC, rD;
    float vN = ld(r0 - 3);
    { float v=vN; vN=ld(r0-2); issue_raw(v); combine_raw(mr0,qr0); }
    { float v=vN; vN=ld(r0-1); issue_raw(v); combine_raw(mr1,qr1); }
    { float v=vN; vN=ld(r0+0); issue_raw(v); combine_raw(mr2,qr2); }
    { float v=vN; vN=ld(r0+1); issue_raw(v); combine_raw(mr3,qr3); rA=v; }
    { float v=vN; vN=ld(r0+2); issue_raw(v); combine_raw(mr4,qr4); rB=v; }
    { float v=vN; vN=ld(r0+3); issue_raw(v); combine_raw(mr5,qr5); rC=v; }
    { float v=vN; vN=ld(r0+4); issue_raw(v); combine_raw(mr6,qr6); rD=v; }
    { float v=vN; vN=ld(r0+5); issue_raw(v); }   // pends = row r0+4

    float normP = 0.f, normP2 = 0.f;
    float pendSL = 0.f, pendPL = 0.f, pendPR = 0.f;
    float firstN = 0.f, dsSave = 0.f;
    const bool dsw = WDS && (lane & 1) && (lane >= 3) && (lane <= 49);

    #pragma unroll 4
    for (int yy = 0; yy < SROWS; ++yy) {
        const int y = r0 + yy;
        // 1) stats for row y-1 (pure VALU; pend bperms issued last iter)
        if (yy > 0) {
            upd(0, normP);
            upd(1, normP * pendSL);
            upd(2, normP * normP2);
            upd(3, normP * pendPL);
            upd(4, normP * pendPR);
        }
        // 2) vertical combine for row y (ring ready since last iter)
        float mu = ((w0*mr0 + w1*mr1) + (w2*mr2 + w3*mr3)) + ((w4*mr4 + w5*mr5) + w6*mr6);
        float s2 = ((w0*qr0 + w1*qr1) + (w2*qr2 + w3*qr3)) + ((w4*qr4 + w5*qr5) + w6*qr6);
        float sig = __builtin_amdgcn_sqrtf(fabsf(s2 - mu * mu));
        float nrm = (rA - mu) * __builtin_amdgcn_rcpf(sig + 1.0f);
        float cur = act ? nrm : 0.f;

        // 3) captures
        if (yy == 0) firstN = cur;
        if constexpr (NSLAB == 2) {
            if (lane == 3)  edgeL[strip][slab][yy] = cur;
            if (lane == 50) edgeR[strip][slab][yy] = cur;
        }
        if (yy == SROWS - 1 && act) lastrow[strip][slab * 48 + lane - 3] = cur;

        // 4) fused 2x2-mean downsample of raw input
        if constexpr (WDS) {
            float hs = rA + __shfl_down(rA, 1);
            if ((y & 1) == 0) dsSave = hs;
            else if (dsw)
                dsout[((size_t)b * (H / 2) + (y >> 1)) * (W / 2) + (gx >> 1)] = 0.25f * (dsSave + hs);
        }

        // 5) issue product bperms for next iteration's stats
        pendSL = bperm(am1, cur);
        pendPL = bperm(am1, normP);
        pendPR = bperm(ap1, normP);
        normP2 = normP; normP = cur;

        // 6) hconv combine for row y+4 (pends issued last iter) + ring shift
        float mh, qh; combine_raw(mh, qh);
        mr0=mr1; mr1=mr2; mr2=mr3; mr3=mr4; mr4=mr5; mr5=mr6; mr6=mh;
        qr0=qr1; qr1=qr2; qr2=qr3; qr3=qr4; qr4=qr5; qr5=qr6; qr6=qh;

        // 7) raw ring shift, issue next raw bperms, prefetch next load
        rA=rB; rB=rC; rC=rD; rD=vHp;
        float vv = vN; vN = ld(y + 6);
        issue_raw(vv);
    }
    // epilogue: stats for the strip's last row
    upd(0, normP);
    upd(1, normP * pendSL);
    upd(2, normP * normP2);
    upd(3, normP * pendPL);
    upd(4, normP * pendPR);

    __syncthreads();

    // ---- row-seam fixup: products of row r0 with block-circular previous row ----
    {
        const int ps = (strip + NSTRIP - 1) % NSTRIP;
        int j  = slab * 48 + (lane - 3);
        int js = act ? j : 0;
        int jm1 = (js + K - 1) % K;
        int jp1 = (js + 1) % K;
        float pv  = act ? lastrow[ps][js]  : 0.f;
        float pvL = act ? lastrow[ps][jm1] : 0.f;
        float pvR = act ? lastrow[ps][jp1] : 0.f;
        upd(2, firstN * pv);
        upd(3, firstN * pvL);
        upd(4, firstN * pvR);
    }

    // ---- column-seam fixup (K=96 only): slab-edge wrap products ----
    if constexpr (NSLAB == 2) {
        if (lane < SROWS) {
            int r = lane;
            if (slab == 0) {
                float c0  = edgeL[strip][0][r];   // n[r][0]
                float e95 = edgeR[strip][1][r];   // n[r][95]
                upd(1, c0 * e95);
                if (r > 0) {
                    upd(3, c0 * edgeR[strip][1][r - 1]);
                    upd(4, edgeR[strip][0][r] * edgeL[strip][1][r - 1]);  // col47 * n[r-1][48]
                }
            } else {
                float c48 = edgeL[strip][1][r];   // n[r][48]
                float e47 = edgeR[strip][0][r];   // n[r][47]
                upd(1, c48 * e47);
                if (r > 0) {
                    upd(3, c48 * edgeR[strip][0][r - 1]);
                    upd(4, edgeR[strip][1][r] * edgeL[strip][0][r - 1]); // col95 * n[r-1][0]
                }
            }
        }
    }

    // ---- reduce: 15 floats via shuffles; counts are wave-uniform scalars ----
    #pragma unroll
    for (int off = 32; off >= 1; off >>= 1)
        #pragma unroll
        for (int s = 0; s < 5; ++s) {
            acc[s][0] += __shfl_down(acc[s][0], off);
            acc[s][1] += __shfl_down(acc[s][1], off);
            acc[s][2] += __shfl_down(acc[s][2], off);
        }
    if (lane == 0) {
        #pragma unroll
        for (int s = 0; s < 5; ++s) {
            redf[wv][s*3+0] = acc[s][0];
            redf[wv][s*3+1] = acc[s][1];
            redf[wv][s*3+2] = acc[s][2];
            redc[wv][s*2+0] = (float)cl[s];
            redc[wv][s*2+1] = (float)cr[s];
        }
    }
    __syncthreads();
    if (tid < 15) {
        stats[((size_t)b * NBLK + bIdx) * 25 + tid] =
            redf[0][tid] + redf[1][tid] + redf[2][tid] + redf[3][tid];
    } else if (tid < 25) {
        int t = tid - 15;
        stats[((size_t)b * NBLK + bIdx) * 25 + tid] =
            redc[0][t] + redc[1][t] + redc[2][t] + redc[3][t];
    }
}

// ---------------- AGGD closed-form + binary-search argmin ----------------
__global__ __launch_bounds__(256) void aggd_kernel(
        const float* __restrict__ stats1, const float* __restrict__ stats2,
        const float* __restrict__ rgam, const float* __restrict__ convt,
        const float* __restrict__ meanf, float* __restrict__ feats) {
    __shared__ float rg[NGRID];
    for (int i = threadIdx.x; i < NGRID; i += 256) rg[i] = rgam[i];
    __syncthreads();

    int gid = blockIdx.x * 256 + threadIdx.x;
    if (gid >= 2 * BATCH * NBLK * 5) return;
    int s = gid % 5; int t = gid / 5;
    int blk = t % NBLK; t /= NBLK;
    int b = t % BATCH; int scale = t / BATCH;

    const float* st = (scale ? stats2 : stats1) + ((size_t)b * NBLK + blk) * 25;
    float sr2 = st[s*3+0], ssq = st[s*3+1], sab = st[s*3+2];
    float cl = st[15 + 2*s], cr = st[15 + 2*s + 1];
    float sl2 = fmaxf(ssq - sr2, 0.f);
    float n = scale ? (48.f * 48.f) : (96.f * 96.f);

    float lstd = sqrtf(sl2 / (cl + 1e-8f));
    float rstd = sqrtf(sr2 / (cr + 1e-8f));
    float gh = lstd / rstd;
    float mab = sab / n;
    float msq = ssq / n;
    float rhat = mab * mab / msq;
    float g2 = gh * gh;
    float x = rhat * (gh * g2 + 1.f) * (gh + 1.f) / ((g2 + 1.f) * (g2 + 1.f));

    // lower_bound: first index with rg[i] >= x  (rg monotone increasing)
    int lo = 0, hi = NGRID;
    while (lo < hi) {
        int mid = (lo + hi) >> 1;
        if (rg[mid] < x) lo = mid + 1; else hi = mid;
    }
    int gi;
    if (lo <= 0) gi = 0;
    else if (lo >= NGRID) gi = NGRID - 1;
    else {
        float dlo = x - rg[lo - 1];   // > 0
        float dhi = rg[lo] - x;       // >= 0
        gi = (dlo <= dhi) ? lo - 1 : lo;   // tie -> lower index (first-min)
    }

    float alpha = (float)(0.2 + 0.001 * (double)gi);
    float cv = convt[gi];
    float lb = lstd * cv, rb = rstd * cv;
    float* fo = feats + ((size_t)b * NBLK + blk) * NFEAT + (scale ? 18 : 0);
    if (s == 0) {
        fo[0] = alpha;
        fo[1] = 0.5f * (lb + rb);
    } else {
        int o = 2 + (s - 1) * 4;
        fo[o]     = alpha;
        fo[o + 1] = (rb - lb) * meanf[gi];
        fo[o + 2] = lb;
        fo[o + 3] = rb;
    }
}

// ---------------- per-batch covariance + solve + score ----------------
// cov = (cov_pris + cov_dist)/2 is SPD (lambda_min >= 0.25) -> no pivoting.
__global__ __launch_bounds__(256) void score_kernel(
        const float* __restrict__ feats, const float* __restrict__ mu_pris,
        const float* __restrict__ cov_pris, float* __restrict__ out) {
    __shared__ float F[NBLK][NFEAT];
    __shared__ double mu[NFEAT];
    __shared__ double A[NFEAT][NFEAT + 1];
    __shared__ double dff[NFEAT];
    __shared__ double xs[NFEAT];
    int b = blockIdx.x, tid = threadIdx.x;
    const float* fp = feats + (size_t)b * NBLK * NFEAT;
    for (int i = tid; i < NBLK * NFEAT; i += 256) F[i / NFEAT][i % NFEAT] = fp[i];
    __syncthreads();
    if (tid < NFEAT) {
        double s = 0.0;
        for (int n = 0; n < NBLK; ++n) s += (double)F[n][tid];
        mu[tid] = s / (double)NBLK;
        dff[tid] = (double)mu_pris[tid] - mu[tid];
    }
    __syncthreads();
    for (int e = tid; e < NFEAT * NFEAT; e += 256) {
        int f = e / NFEAT, g = e % NFEAT;
        double mf = mu[f], mg = mu[g];
        double s = 0.0;
        for (int n = 0; n < NBLK; ++n) s += ((double)F[n][f] - mf) * ((double)F[n][g] - mg);
        A[f][g] = (s / (double)(NBLK - 1) + (double)cov_pris[f * NFEAT + g]) * 0.5;
    }
    if (tid < NFEAT) A[tid][NFEAT] = dff[tid];
    // forward elimination: one barrier per k (fac folded into update)
    for (int k = 0; k < NFEAT - 1; ++k) {
        __syncthreads();
        double rk = 1.0 / A[k][k];
        for (int e = tid; e < NFEAT * (NFEAT + 1); e += 256) {
            int r = e / (NFEAT + 1), c = e % (NFEAT + 1);
            if (r > k && c > k) A[r][c] -= (A[r][k] * rk) * A[k][c];
        }
    }
    __syncthreads();
    // back substitution: one barrier per i (self-carried row updates)
    for (int i = NFEAT - 1; i >= 0; --i) {
        if (tid == i) xs[i] = A[i][NFEAT] / A[i][i];
        __syncthreads();
        if (tid < i) A[tid][NFEAT] -= A[tid][i] * xs[i];
    }
    __syncthreads();
    if (tid == 0) {
        double quad = 0.0;
        for (int i = 0; i < NFEAT; ++i) quad += dff[i] * xs[i];
        out[b] = (float)sqrt(fmax(quad, 0.0));
    }
}

// ---------------- launch ----------------
extern "C" void kernel_launch(void* const* d_in, const int* in_sizes, int n_in,
                              void* d_out, int out_size, void* d_ws, size_t ws_size,
                              hipStream_t stream) {
    const float* img      = (const float*)d_in[0];
    const float* mu_pris  = (const float*)d_in[1];
    const float* cov_pris = (const float*)d_in[2];
    float* out = (float*)d_out;
    float* ws = (float*)d_ws;

    float* rgam  = ws;                 // 9801 (pad to 9856)
    float* convt = rgam + 9856;
    float* meanf = convt + 9856;
    float* w1d   = meanf + 9856;       // 8
    float* stats1 = w1d + 8;                           // 16*121*25
    float* stats2 = stats1 + BATCH * NBLK * 25;
    float* feats  = stats2 + BATCH * NBLK * 25;        // 16*121*36
    float* dsimg  = feats + BATCH * NBLK * NFEAT;      // 16*528*528

    init_tables<<<(NGRID + 255) / 256, 256, 0, stream>>>(rgam, convt, meanf, w1d);

    fused_mscn_stats<96, true><<<dim3(NBLK, BATCH), 256, 0, stream>>>(
        img, dsimg, w1d, stats1);
    fused_mscn_stats<48, false><<<dim3(NBLK, BATCH), 256, 0, stream>>>(
        dsimg, nullptr, w1d, stats2);

    aggd_kernel<<<(2 * BATCH * NBLK * 5 + 255) / 256, 256, 0, stream>>>(
        stats1, stats2, rgam, convt, meanf, feats);

    score_kernel<<<BATCH, 256, 0, stream>>>(feats, mu_pris, cov_pris, out);
}